// Round 1
// baseline (919.329 us; speedup 1.0000x reference)
//
#include <hip/hip_runtime.h>
#include <hip/hip_bf16.h>
#include <stdint.h>

#define HIDDEN 2048
#define BATCH 16384
#define NUM_OPS 3
#define NTILES 131
#define M_CAP (NTILES * 128)   // 16768: 16384 + up to 3*128 of segment padding

typedef __attribute__((ext_vector_type(4))) float f32x4;
typedef __attribute__((ext_vector_type(8))) short short8;
typedef __attribute__((ext_vector_type(8))) __bf16 bf16x8;

// ---- workspace layout (bytes) ----
static constexpr size_t XB_SZ   = (size_t)M_CAP * HIDDEN * 2;        // sorted x, bf16
static constexpr size_t H_SZ    = XB_SZ;                             // hidden, bf16
static constexpr size_t WT_SZ   = (size_t)NUM_OPS * HIDDEN * HIDDEN * 2; // transposed bf16 weights
static constexpr size_t PERM_SZ = (size_t)M_CAP * 4;
// total ~188 MB

__device__ __forceinline__ unsigned f2bf(float f) {
  unsigned u = __float_as_uint(f);
  return (u + 0x7FFFu + ((u >> 16) & 1u)) >> 16;   // RNE
}

__device__ __forceinline__ void async_ld16(const void* g, void* l) {
  __builtin_amdgcn_global_load_lds(
      (__attribute__((address_space(1))) void*)(void*)g,
      (__attribute__((address_space(3))) void*)l, 16, 0, 0);
}

// ---- tiny partition kernels ----
__global__ __launch_bounds__(256) void k_count(const int* __restrict__ ops,
                                               int* __restrict__ cnt) {
  int b = blockIdx.x * 256 + threadIdx.x;
  if (b < BATCH) atomicAdd(&cnt[ops[b]], 1);
}

__global__ void k_scan(const int* __restrict__ cnt, int* __restrict__ seg,
                       int* __restrict__ te) {
  if (threadIdx.x == 0 && blockIdx.x == 0) {
    int a0 = (cnt[0] + 127) & ~127;
    int a1 = (cnt[1] + 127) & ~127;
    int a2 = (cnt[2] + 127) & ~127;
    seg[0] = 0; seg[1] = a0; seg[2] = a0 + a1; seg[3] = a0 + a1 + a2;
    for (int t = 0; t < NTILES; t++) {
      int row = t * 128;
      int ex = -1;
      if (row < a0) ex = 0;
      else if (row < a0 + a1) ex = 1;
      else if (row < a0 + a1 + a2) ex = 2;
      te[t] = ex;
    }
  }
}

__global__ __launch_bounds__(256) void k_perm(const int* __restrict__ ops,
                                              const int* __restrict__ seg,
                                              int* __restrict__ c2,
                                              int* __restrict__ perm) {
  int b = blockIdx.x * 256 + threadIdx.x;
  if (b < BATCH) {
    int e = ops[b];
    int lp = atomicAdd(&c2[e], 1);
    perm[seg[e] + lp] = b;
  }
}

// gather + fp32->bf16: one block per (sorted) row; pad rows (perm=-1) zeroed
__global__ __launch_bounds__(256) void k_gather(const float* __restrict__ x,
                                                const int* __restrict__ perm,
                                                short* __restrict__ xb) {
  int pos = blockIdx.x;
  int b = perm[pos];
  int tid = threadIdx.x;
  uint4 o;
  if (b < 0) {
    o = make_uint4(0u, 0u, 0u, 0u);
  } else {
    const float4* xs = (const float4*)(x + (size_t)b * HIDDEN + tid * 8);
    float4 f0 = xs[0], f1 = xs[1];
    o.x = f2bf(f0.x) | (f2bf(f0.y) << 16);
    o.y = f2bf(f0.z) | (f2bf(f0.w) << 16);
    o.z = f2bf(f1.x) | (f2bf(f1.y) << 16);
    o.w = f2bf(f1.z) | (f2bf(f1.w) << 16);
  }
  *(uint4*)(xb + (size_t)pos * HIDDEN + tid * 8) = o;
}

// W[e][k][n] fp32  ->  Wt[e][n][k] bf16   (64x64 LDS tiles)
__global__ __launch_bounds__(256) void k_transpose(const float* __restrict__ W1,
                                                   const float* __restrict__ W2,
                                                   short* __restrict__ W1t,
                                                   short* __restrict__ W2t) {
  __shared__ float t[64][65];
  int z = blockIdx.z;  // 0..2: W1 experts, 3..5: W2 experts
  const float* src = (z < 3) ? (W1 + (size_t)z * HIDDEN * HIDDEN)
                             : (W2 + (size_t)(z - 3) * HIDDEN * HIDDEN);
  short* dst = (z < 3) ? (W1t + (size_t)z * HIDDEN * HIDDEN)
                       : (W2t + (size_t)(z - 3) * HIDDEN * HIDDEN);
  int k0 = blockIdx.y * 64;
  int n0 = blockIdx.x * 64;
  int c = threadIdx.x & 63, rb = threadIdx.x >> 6;
#pragma unroll
  for (int i = 0; i < 16; i++) {
    int r = i * 4 + rb;
    t[r][c] = src[(size_t)(k0 + r) * HIDDEN + n0 + c];
  }
  __syncthreads();
#pragma unroll
  for (int i = 0; i < 16; i++) {
    int r = i * 4 + rb;
    dst[(size_t)(n0 + r) * HIDDEN + k0 + c] = (short)f2bf(t[c][r]);
  }
}

// ---- m97-style bf16 GEMM, 128x128 tile, BK=64, fused bias+ReLU epilogue ----
// A: [M_CAP][2048] bf16 row-major (expert-sorted). Wt: [e][n][k] bf16.
// SECOND=0: write h bf16.  SECOND=1: scatter fp32 rows via perm into out.
template <int SECOND>
__global__ __launch_bounds__(256)
void gemm_fused(const short* __restrict__ A, const short* __restrict__ Wt,
                const float* __restrict__ bias, const int* __restrict__ te,
                const int* __restrict__ perm, short* __restrict__ Hout,
                float* __restrict__ Yout) {
  __shared__ short As[128 * 64];
  __shared__ short Bs[128 * 64];

  const int e = te[blockIdx.y];
  if (e < 0) return;

  const int tid = threadIdx.x;
  const int wave = tid >> 6;
  const int lane = tid & 63;
  const int quad = lane >> 4;
  const int l16 = lane & 15;
  const int wm = (wave >> 1) * 64;
  const int wn = (wave & 1) * 64;

  const short* Ag = A + (size_t)blockIdx.y * 128 * HIDDEN;
  const short* Bg = Wt + (size_t)e * HIDDEN * HIDDEN + (size_t)blockIdx.x * 128 * HIDDEN;

  const int crow = tid >> 3;        // + i*32 per staging iter
  const int ckp = (tid & 7) * 8;

  f32x4 acc[4][4] = {};

  for (int k0 = 0; k0 < HIDDEN; k0 += 64) {
#pragma unroll
    for (int i = 0; i < 4; i++)
      async_ld16(Ag + (size_t)(i * 32 + crow) * HIDDEN + (k0 + ckp),
                 As + (i * 256 + wave * 64) * 8);
#pragma unroll
    for (int i = 0; i < 4; i++)
      async_ld16(Bg + (size_t)(i * 32 + crow) * HIDDEN + (k0 + ckp),
                 Bs + (i * 256 + wave * 64) * 8);
    __syncthreads();
#pragma unroll
    for (int kk = 0; kk < 64; kk += 32) {
      bf16x8 af[4], bfr[4];
#pragma unroll
      for (int i = 0; i < 4; i++) {
        short8 s = *(const short8*)(As + (wm + i * 16 + l16) * 64 + kk + quad * 8);
        af[i] = __builtin_bit_cast(bf16x8, s);
      }
#pragma unroll
      for (int j = 0; j < 4; j++) {
        short8 s = *(const short8*)(Bs + (wn + j * 16 + l16) * 64 + kk + quad * 8);
        bfr[j] = __builtin_bit_cast(bf16x8, s);
      }
#pragma unroll
      for (int i = 0; i < 4; i++)
#pragma unroll
        for (int j = 0; j < 4; j++)
          acc[i][j] = __builtin_amdgcn_mfma_f32_16x16x32_bf16(af[i], bfr[j], acc[i][j], 0, 0, 0);
    }
    __syncthreads();
  }

  // epilogue: C/D layout col=lane&15, row=quad*4+reg  (m89/m91-verified)
  const int rowbase = blockIdx.y * 128 + wm + quad * 4;
  const int colbase = blockIdx.x * 128 + wn + l16;
#pragma unroll
  for (int j = 0; j < 4; j++) {
    const int n = colbase + j * 16;
    const float bv = bias[e * HIDDEN + n];
#pragma unroll
    for (int i = 0; i < 4; i++) {
      const int m0 = rowbase + i * 16;
#pragma unroll
      for (int r = 0; r < 4; r++) {
        float v = acc[i][j][r] + bv;
        v = v > 0.0f ? v : 0.0f;
        const int m = m0 + r;
        if (SECOND) {
          const int b = perm[m];
          if (b >= 0) Yout[(size_t)b * HIDDEN + n] = v;
        } else {
          Hout[(size_t)m * HIDDEN + n] = (short)f2bf(v);
        }
      }
    }
  }
}

extern "C" void kernel_launch(void* const* d_in, const int* in_sizes, int n_in,
                              void* d_out, int out_size, void* d_ws, size_t ws_size,
                              hipStream_t stream) {
  const float* x  = (const float*)d_in[0];
  const float* W1 = (const float*)d_in[1];
  const float* b1 = (const float*)d_in[2];
  const float* W2 = (const float*)d_in[3];
  const float* b2 = (const float*)d_in[4];
  const int* ops  = (const int*)d_in[5];
  float* out = (float*)d_out;

  char* ws = (char*)d_ws;
  short* xb  = (short*)(ws);
  short* h   = (short*)(ws + XB_SZ);
  short* w1t = (short*)(ws + XB_SZ + H_SZ);
  short* w2t = (short*)(ws + XB_SZ + H_SZ + WT_SZ);
  int* perm  = (int*)(ws + XB_SZ + H_SZ + 2 * WT_SZ);
  int* meta  = (int*)(ws + XB_SZ + H_SZ + 2 * WT_SZ + PERM_SZ);
  int* cnt = meta;       // [3]
  int* c2  = meta + 4;   // [3]
  int* seg = meta + 8;   // [4]
  int* te  = meta + 16;  // [NTILES]

  hipMemsetAsync(meta, 0, 32, stream);                       // cnt + c2
  hipMemsetAsync(perm, 0xFF, PERM_SZ, stream);               // perm = -1
  k_count<<<BATCH / 256, 256, 0, stream>>>(ops, cnt);
  k_scan<<<1, 64, 0, stream>>>(cnt, seg, te);
  k_perm<<<BATCH / 256, 256, 0, stream>>>(ops, seg, c2, perm);
  k_gather<<<M_CAP, 256, 0, stream>>>(x, perm, xb);
  k_transpose<<<dim3(32, 32, 6), 256, 0, stream>>>(W1, W2, w1t, w2t);
  gemm_fused<0><<<dim3(16, NTILES), 256, 0, stream>>>(xb, w1t, b1, te, perm, h, nullptr);
  gemm_fused<1><<<dim3(16, NTILES), 256, 0, stream>>>(h, w2t, b2, te, perm, nullptr, out);
}

// Round 2
// 731.580 us; speedup vs baseline: 1.2566x; 1.2566x over previous
//
#include <hip/hip_runtime.h>
#include <hip/hip_bf16.h>
#include <stdint.h>

#define HIDDEN 2048
#define BATCH 16384
#define NUM_OPS 3
#define NTILES 131
#define M_CAP (NTILES * 128)   // 16768: 16384 + up to 3*128 of segment padding

typedef __attribute__((ext_vector_type(4))) float f32x4;
typedef __attribute__((ext_vector_type(8))) short short8;
typedef __attribute__((ext_vector_type(8))) __bf16 bf16x8;

// ---- workspace layout (bytes) ----
static constexpr size_t XB_SZ   = (size_t)M_CAP * HIDDEN * 2;        // sorted x, bf16
static constexpr size_t H_SZ    = XB_SZ;                             // hidden, bf16
static constexpr size_t WT_SZ   = (size_t)NUM_OPS * HIDDEN * HIDDEN * 2; // transposed bf16 weights
static constexpr size_t PERM_SZ = (size_t)M_CAP * 4;

__device__ __forceinline__ unsigned f2bf(float f) {
  unsigned u = __float_as_uint(f);
  return (u + 0x7FFFu + ((u >> 16) & 1u)) >> 16;   // RNE
}

__device__ __forceinline__ void async_ld16(const void* g, void* l) {
  __builtin_amdgcn_global_load_lds(
      (__attribute__((address_space(1))) void*)(void*)g,
      (__attribute__((address_space(3))) void*)l, 16, 0, 0);
}

// ---- tiny partition kernels (ballot-aggregated atomics: 16384 -> <=768) ----
__global__ __launch_bounds__(256) void k_count(const int* __restrict__ ops,
                                               int* __restrict__ cnt) {
  int b = blockIdx.x * 256 + threadIdx.x;
  int e = (b < BATCH) ? ops[b] : -1;
  int lane = threadIdx.x & 63;
#pragma unroll
  for (int ee = 0; ee < NUM_OPS; ee++) {
    unsigned long long m = __ballot(e == ee);
    if (lane == 0 && m) atomicAdd(&cnt[ee], __popcll(m));
  }
}

__global__ void k_scan(const int* __restrict__ cnt, int* __restrict__ seg,
                       int* __restrict__ te) {
  if (threadIdx.x == 0 && blockIdx.x == 0) {
    int a0 = (cnt[0] + 127) & ~127;
    int a1 = (cnt[1] + 127) & ~127;
    int a2 = (cnt[2] + 127) & ~127;
    seg[0] = 0; seg[1] = a0; seg[2] = a0 + a1; seg[3] = a0 + a1 + a2;
    for (int t = 0; t < NTILES; t++) {
      int row = t * 128;
      int ex = -1;
      if (row < a0) ex = 0;
      else if (row < a0 + a1) ex = 1;
      else if (row < a0 + a1 + a2) ex = 2;
      te[t] = ex;
    }
  }
}

__global__ __launch_bounds__(256) void k_perm(const int* __restrict__ ops,
                                              const int* __restrict__ seg,
                                              int* __restrict__ c2,
                                              int* __restrict__ perm) {
  int b = blockIdx.x * 256 + threadIdx.x;
  int e = (b < BATCH) ? ops[b] : -1;
  int lane = threadIdx.x & 63;
#pragma unroll
  for (int ee = 0; ee < NUM_OPS; ee++) {
    unsigned long long m = __ballot(e == ee);
    if (m) {
      int base = 0;
      if (lane == 0) base = atomicAdd(&c2[ee], __popcll(m));
      base = __shfl(base, 0);
      if (e == ee) {
        int myoff = __popcll(m & ((1ull << lane) - 1ull));
        perm[seg[ee] + base + myoff] = b;
      }
    }
  }
}

// gather + fp32->bf16: one block per (sorted) row; pad rows (perm=-1) zeroed
__global__ __launch_bounds__(256) void k_gather(const float* __restrict__ x,
                                                const int* __restrict__ perm,
                                                short* __restrict__ xb) {
  int pos = blockIdx.x;
  int b = perm[pos];
  int tid = threadIdx.x;
  uint4 o;
  if (b < 0) {
    o = make_uint4(0u, 0u, 0u, 0u);
  } else {
    const float4* xs = (const float4*)(x + (size_t)b * HIDDEN + tid * 8);
    float4 f0 = xs[0], f1 = xs[1];
    o.x = f2bf(f0.x) | (f2bf(f0.y) << 16);
    o.y = f2bf(f0.z) | (f2bf(f0.w) << 16);
    o.z = f2bf(f1.x) | (f2bf(f1.y) << 16);
    o.w = f2bf(f1.z) | (f2bf(f1.w) << 16);
  }
  *(uint4*)(xb + (size_t)pos * HIDDEN + tid * 8) = o;
}

// W[e][k][n] fp32 -> Wt[e][n][k] bf16, 64x64 tiles, 16B coalesced writes
__global__ __launch_bounds__(256) void k_transpose(const float* __restrict__ W1,
                                                   const float* __restrict__ W2,
                                                   short* __restrict__ W1t,
                                                   short* __restrict__ W2t) {
  __shared__ float t[64][65];
  int z = blockIdx.z;  // 0..2: W1 experts, 3..5: W2 experts
  const float* src = (z < 3) ? (W1 + (size_t)z * HIDDEN * HIDDEN)
                             : (W2 + (size_t)(z - 3) * HIDDEN * HIDDEN);
  short* dst = (z < 3) ? (W1t + (size_t)z * HIDDEN * HIDDEN)
                       : (W2t + (size_t)(z - 3) * HIDDEN * HIDDEN);
  int k0 = blockIdx.y * 64;
  int n0 = blockIdx.x * 64;
  int tid = threadIdx.x;
  // load: t[k][n], float4 per thread, 16 k-rows per pass x 4
  {
    int kk = tid >> 4, n4 = (tid & 15) * 4;
#pragma unroll
    for (int p = 0; p < 4; p++) {
      int k = p * 16 + kk;
      *(float4*)&t[k][n4] = *(const float4*)&src[(size_t)(k0 + k) * HIDDEN + n0 + n4];
    }
  }
  __syncthreads();
  // store: dst[n][k], 8 shorts (16B) per thread per pass, 2 passes
#pragma unroll
  for (int p = 0; p < 2; p++) {
    int q = p * 256 + tid;
    int n = q >> 3, uc = q & 7;
    uint4 o;
    unsigned* po = (unsigned*)&o;
#pragma unroll
    for (int j = 0; j < 4; j++) {
      float a = t[uc * 8 + 2 * j][n];
      float c = t[uc * 8 + 2 * j + 1][n];
      po[j] = f2bf(a) | (f2bf(c) << 16);
    }
    *(uint4*)&dst[(size_t)(n0 + n) * HIDDEN + k0 + uc * 8] = o;
  }
}

// ---- m97-style bf16 GEMM, 128x128 tile, BK=64, XOR-swizzled LDS ----
// LDS As[r][c] holds global chunk (c ^ (r&7)); fragment reads col cc^(row&7).
// => ds_read_b128: 8 consecutive lanes hit 8 distinct 16B columns (conflict-free)
// SECOND=0: write h bf16.  SECOND=1: scatter fp32 rows via perm into out.
template <int SECOND>
__global__ __launch_bounds__(256)
void gemm_fused(const short* __restrict__ A, const short* __restrict__ Wt,
                const float* __restrict__ bias, const int* __restrict__ te,
                const int* __restrict__ perm, short* __restrict__ Hout,
                float* __restrict__ Yout) {
  __shared__ short As[128 * 64];
  __shared__ short Bs[128 * 64];

  const int e = te[blockIdx.y];
  if (e < 0) return;

  const int tid = threadIdx.x;
  const int wave = tid >> 6;
  const int lane = tid & 63;
  const int quad = lane >> 4;
  const int l16 = lane & 15;
  const int wm = (wave >> 1) * 64;
  const int wn = (wave & 1) * 64;

  const short* Ag = A + (size_t)blockIdx.y * 128 * HIDDEN;
  const short* Bg = Wt + (size_t)e * HIDDEN * HIDDEN + (size_t)blockIdx.x * 128 * HIDDEN;

  const int crow = tid >> 3;                       // row within 32-row staging group
  const int csw = ((tid & 7) ^ (crow & 7)) * 8;    // swizzled k-chunk (shorts)

  f32x4 acc[4][4] = {};

  for (int k0 = 0; k0 < HIDDEN; k0 += 64) {
#pragma unroll
    for (int i = 0; i < 4; i++)
      async_ld16(Ag + (size_t)(i * 32 + crow) * HIDDEN + (k0 + csw),
                 As + (i * 256 + wave * 64) * 8);
#pragma unroll
    for (int i = 0; i < 4; i++)
      async_ld16(Bg + (size_t)(i * 32 + crow) * HIDDEN + (k0 + csw),
                 Bs + (i * 256 + wave * 64) * 8);
    __syncthreads();
#pragma unroll
    for (int kk = 0; kk < 64; kk += 32) {
      bf16x8 af[4], bfr[4];
#pragma unroll
      for (int i = 0; i < 4; i++) {
        int row = wm + i * 16 + l16;
        int col = ((kk >> 3) + quad) ^ (row & 7);
        short8 s = *(const short8*)(As + row * 64 + col * 8);
        af[i] = __builtin_bit_cast(bf16x8, s);
      }
#pragma unroll
      for (int j = 0; j < 4; j++) {
        int row = wn + j * 16 + l16;
        int col = ((kk >> 3) + quad) ^ (row & 7);
        short8 s = *(const short8*)(Bs + row * 64 + col * 8);
        bfr[j] = __builtin_bit_cast(bf16x8, s);
      }
#pragma unroll
      for (int i = 0; i < 4; i++)
#pragma unroll
        for (int j = 0; j < 4; j++)
          acc[i][j] = __builtin_amdgcn_mfma_f32_16x16x32_bf16(af[i], bfr[j], acc[i][j], 0, 0, 0);
    }
    __syncthreads();
  }

  // epilogue: C/D layout col=lane&15, row=quad*4+reg  (m89/m91-verified)
  const int rowbase = blockIdx.y * 128 + wm + quad * 4;
  const int colbase = blockIdx.x * 128 + wn + l16;
#pragma unroll
  for (int j = 0; j < 4; j++) {
    const int n = colbase + j * 16;
    const float bv = bias[e * HIDDEN + n];
#pragma unroll
    for (int i = 0; i < 4; i++) {
      const int m0 = rowbase + i * 16;
#pragma unroll
      for (int r = 0; r < 4; r++) {
        float v = acc[i][j][r] + bv;
        v = v > 0.0f ? v : 0.0f;
        const int m = m0 + r;
        if (SECOND) {
          const int b = perm[m];
          if (b >= 0) Yout[(size_t)b * HIDDEN + n] = v;
        } else {
          Hout[(size_t)m * HIDDEN + n] = (short)f2bf(v);
        }
      }
    }
  }
}

extern "C" void kernel_launch(void* const* d_in, const int* in_sizes, int n_in,
                              void* d_out, int out_size, void* d_ws, size_t ws_size,
                              hipStream_t stream) {
  const float* x  = (const float*)d_in[0];
  const float* W1 = (const float*)d_in[1];
  const float* b1 = (const float*)d_in[2];
  const float* W2 = (const float*)d_in[3];
  const float* b2 = (const float*)d_in[4];
  const int* ops  = (const int*)d_in[5];
  float* out = (float*)d_out;

  char* ws = (char*)d_ws;
  short* xb  = (short*)(ws);
  short* h   = (short*)(ws + XB_SZ);
  short* w1t = (short*)(ws + XB_SZ + H_SZ);
  short* w2t = (short*)(ws + XB_SZ + H_SZ + WT_SZ);
  int* perm  = (int*)(ws + XB_SZ + H_SZ + 2 * WT_SZ);
  int* meta  = (int*)(ws + XB_SZ + H_SZ + 2 * WT_SZ + PERM_SZ);
  int* cnt = meta;       // [3]
  int* c2  = meta + 4;   // [3]
  int* seg = meta + 8;   // [4]
  int* te  = meta + 16;  // [NTILES]

  hipMemsetAsync(meta, 0, 32, stream);                       // cnt + c2
  hipMemsetAsync(perm, 0xFF, PERM_SZ, stream);               // perm = -1
  k_count<<<BATCH / 256, 256, 0, stream>>>(ops, cnt);
  k_scan<<<1, 64, 0, stream>>>(cnt, seg, te);
  k_perm<<<BATCH / 256, 256, 0, stream>>>(ops, seg, c2, perm);
  k_gather<<<M_CAP, 256, 0, stream>>>(x, perm, xb);
  k_transpose<<<dim3(32, 32, 6), 256, 0, stream>>>(W1, W2, w1t, w2t);
  gemm_fused<0><<<dim3(16, NTILES), 256, 0, stream>>>(xb, w1t, b1, te, perm, h, nullptr);
  gemm_fused<1><<<dim3(16, NTILES), 256, 0, stream>>>(h, w2t, b2, te, perm, nullptr, out);
}

// Round 3
// 723.384 us; speedup vs baseline: 1.2709x; 1.0113x over previous
//
#include <hip/hip_runtime.h>
#include <hip/hip_bf16.h>
#include <stdint.h>

#define HIDDEN 2048
#define BATCH 16384
#define NUM_OPS 3
#define NTILES 131
#define M_CAP (NTILES * 128)   // 16768: 16384 + up to 3*128 of segment padding
#define NXT 16                 // n-tiles per GEMM (2048/128)

typedef __attribute__((ext_vector_type(4))) float f32x4;
typedef __attribute__((ext_vector_type(8))) short short8;
typedef __attribute__((ext_vector_type(8))) __bf16 bf16x8;

// ---- workspace layout (bytes) ----
static constexpr size_t XB_SZ   = (size_t)M_CAP * HIDDEN * 2;        // sorted x, bf16
static constexpr size_t H_SZ    = XB_SZ;                             // hidden, bf16
static constexpr size_t WT_SZ   = (size_t)NUM_OPS * HIDDEN * HIDDEN * 2; // transposed bf16 weights
static constexpr size_t PERM_SZ = (size_t)M_CAP * 4;

__device__ __forceinline__ unsigned f2bf(float f) {
  unsigned u = __float_as_uint(f);
  return (u + 0x7FFFu + ((u >> 16) & 1u)) >> 16;   // RNE
}

__device__ __forceinline__ void async_ld16(const void* g, void* l) {
  __builtin_amdgcn_global_load_lds(
      (__attribute__((address_space(1))) void*)(void*)g,
      (__attribute__((address_space(3))) void*)l, 16, 0, 0);
}

// ---- partition kernels (ballot-aggregated atomics) ----
// also initializes perm[] = -1 (replaces a memsetAsync launch)
__global__ __launch_bounds__(256) void k_count(const int* __restrict__ ops,
                                               int* __restrict__ cnt,
                                               int* __restrict__ perm) {
  int i = blockIdx.x * 256 + threadIdx.x;
  if (i < M_CAP) perm[i] = -1;
  int e = (i < BATCH) ? ops[i] : -1;
  int lane = threadIdx.x & 63;
#pragma unroll
  for (int ee = 0; ee < NUM_OPS; ee++) {
    unsigned long long m = __ballot(e == ee);
    if (lane == 0 && m) atomicAdd(&cnt[ee], __popcll(m));
  }
}

__global__ void k_scan(const int* __restrict__ cnt, int* __restrict__ seg,
                       int* __restrict__ te) {
  int a0 = (cnt[0] + 127) & ~127;
  int a1 = (cnt[1] + 127) & ~127;
  int a2 = (cnt[2] + 127) & ~127;
  if (threadIdx.x == 0) {
    seg[0] = 0; seg[1] = a0; seg[2] = a0 + a1; seg[3] = a0 + a1 + a2;
  }
  for (int t = threadIdx.x; t < NTILES; t += 64) {
    int row = t * 128;
    int ex = -1;
    if (row < a0) ex = 0;
    else if (row < a0 + a1) ex = 1;
    else if (row < a0 + a1 + a2) ex = 2;
    te[t] = ex;
  }
}

__global__ __launch_bounds__(256) void k_perm(const int* __restrict__ ops,
                                              const int* __restrict__ seg,
                                              int* __restrict__ c2,
                                              int* __restrict__ perm) {
  int b = blockIdx.x * 256 + threadIdx.x;
  int e = (b < BATCH) ? ops[b] : -1;
  int lane = threadIdx.x & 63;
#pragma unroll
  for (int ee = 0; ee < NUM_OPS; ee++) {
    unsigned long long m = __ballot(e == ee);
    if (m) {
      int base = 0;
      if (lane == 0) base = atomicAdd(&c2[ee], __popcll(m));
      base = __shfl(base, 0);
      if (e == ee) {
        int myoff = __popcll(m & ((1ull << lane) - 1ull));
        perm[seg[ee] + base + myoff] = b;
      }
    }
  }
}

// ---- fused prep: gather+convert x (blocks [0,M_CAP)) and
//      W[e][k][n] fp32 -> Wt[e][n][k] bf16 (blocks [M_CAP, M_CAP+6144)) ----
__global__ __launch_bounds__(256) void k_prep(const float* __restrict__ x,
                                              const int* __restrict__ perm,
                                              short* __restrict__ xb,
                                              const float* __restrict__ W1,
                                              const float* __restrict__ W2,
                                              short* __restrict__ W1t,
                                              short* __restrict__ W2t) {
  int tid = threadIdx.x;
  if (blockIdx.x < M_CAP) {
    // gather + fp32->bf16, one block per sorted row; pad rows zeroed
    int pos = blockIdx.x;
    int b = perm[pos];
    uint4 o;
    if (b < 0) {
      o = make_uint4(0u, 0u, 0u, 0u);
    } else {
      const float4* xs = (const float4*)(x + (size_t)b * HIDDEN + tid * 8);
      float4 f0 = xs[0], f1 = xs[1];
      o.x = f2bf(f0.x) | (f2bf(f0.y) << 16);
      o.y = f2bf(f0.z) | (f2bf(f0.w) << 16);
      o.z = f2bf(f1.x) | (f2bf(f1.y) << 16);
      o.w = f2bf(f1.z) | (f2bf(f1.w) << 16);
    }
    *(uint4*)(xb + (size_t)pos * HIDDEN + tid * 8) = o;
  } else {
    // transpose: 64x64 tiles, 16B coalesced loads and stores
    __shared__ float t[64][65];
    int q = blockIdx.x - M_CAP;     // 0..6143
    int z = q >> 10;                // 0..5: expert*layer
    int rem = q & 1023;
    int by = rem >> 5, bx = rem & 31;
    const float* src = (z < 3) ? (W1 + (size_t)z * HIDDEN * HIDDEN)
                               : (W2 + (size_t)(z - 3) * HIDDEN * HIDDEN);
    short* dst = (z < 3) ? (W1t + (size_t)z * HIDDEN * HIDDEN)
                         : (W2t + (size_t)(z - 3) * HIDDEN * HIDDEN);
    int k0 = by * 64;
    int n0 = bx * 64;
    {
      int kk = tid >> 4, n4 = (tid & 15) * 4;
#pragma unroll
      for (int p = 0; p < 4; p++) {
        int k = p * 16 + kk;
        *(float4*)&t[k][n4] = *(const float4*)&src[(size_t)(k0 + k) * HIDDEN + n0 + n4];
      }
    }
    __syncthreads();
#pragma unroll
    for (int p = 0; p < 2; p++) {
      int qq = p * 256 + tid;
      int n = qq >> 3, uc = qq & 7;
      uint4 o;
      unsigned* po = (unsigned*)&o;
#pragma unroll
      for (int j = 0; j < 4; j++) {
        float a = t[uc * 8 + 2 * j][n];
        float c = t[uc * 8 + 2 * j + 1][n];
        po[j] = f2bf(a) | (f2bf(c) << 16);
      }
      *(uint4*)&dst[(size_t)(n0 + n) * HIDDEN + k0 + uc * 8] = o;
    }
  }
}

// ---- m97-style bf16 GEMM, 128x128 tile, BK=64, XOR-swizzled LDS ----
// 1D grid with XCD-affinity swizzle: xcd = lin&7 gets x-tiles {xcd, xcd+8}
// only => per-XCD B working set ~1 MB (L2-resident); consecutive slots share
// the same A tile (L2 hit on 2nd read).
// SECOND=0: write h bf16.  SECOND=1: scatter fp32 rows via perm into out.
template <int SECOND>
__global__ __launch_bounds__(256)
void gemm_fused(const short* __restrict__ A, const short* __restrict__ Wt,
                const float* __restrict__ bias, const int* __restrict__ te,
                const int* __restrict__ perm, short* __restrict__ Hout,
                float* __restrict__ Yout) {
  __shared__ short As[128 * 64];
  __shared__ short Bs[128 * 64];

  const int lin = blockIdx.x;
  const int slot = lin >> 3;
  const int yt = slot >> 1;                    // m-tile 0..130
  const int xt = (lin & 7) + 8 * (slot & 1);   // n-tile 0..15

  const int e = te[yt];
  if (e < 0) return;

  const int tid = threadIdx.x;
  const int wave = tid >> 6;
  const int lane = tid & 63;
  const int quad = lane >> 4;
  const int l16 = lane & 15;
  const int wm = (wave >> 1) * 64;
  const int wn = (wave & 1) * 64;

  const short* Ag = A + (size_t)yt * 128 * HIDDEN;
  const short* Bg = Wt + (size_t)e * HIDDEN * HIDDEN + (size_t)xt * 128 * HIDDEN;

  const int crow = tid >> 3;                       // row within 32-row staging group
  const int csw = ((tid & 7) ^ (crow & 7)) * 8;    // swizzled k-chunk (shorts)

  f32x4 acc[4][4] = {};

  for (int k0 = 0; k0 < HIDDEN; k0 += 64) {
#pragma unroll
    for (int i = 0; i < 4; i++)
      async_ld16(Ag + (size_t)(i * 32 + crow) * HIDDEN + (k0 + csw),
                 As + (i * 256 + wave * 64) * 8);
#pragma unroll
    for (int i = 0; i < 4; i++)
      async_ld16(Bg + (size_t)(i * 32 + crow) * HIDDEN + (k0 + csw),
                 Bs + (i * 256 + wave * 64) * 8);
    __syncthreads();
#pragma unroll
    for (int kk = 0; kk < 64; kk += 32) {
      bf16x8 af[4], bfr[4];
#pragma unroll
      for (int i = 0; i < 4; i++) {
        int row = wm + i * 16 + l16;
        int col = ((kk >> 3) + quad) ^ (row & 7);
        short8 s = *(const short8*)(As + row * 64 + col * 8);
        af[i] = __builtin_bit_cast(bf16x8, s);
      }
#pragma unroll
      for (int j = 0; j < 4; j++) {
        int row = wn + j * 16 + l16;
        int col = ((kk >> 3) + quad) ^ (row & 7);
        short8 s = *(const short8*)(Bs + row * 64 + col * 8);
        bfr[j] = __builtin_bit_cast(bf16x8, s);
      }
#pragma unroll
      for (int i = 0; i < 4; i++)
#pragma unroll
        for (int j = 0; j < 4; j++)
          acc[i][j] = __builtin_amdgcn_mfma_f32_16x16x32_bf16(af[i], bfr[j], acc[i][j], 0, 0, 0);
    }
    __syncthreads();
  }

  // epilogue: C/D layout col=lane&15, row=quad*4+reg  (m89/m91-verified)
  const int rowbase = yt * 128 + wm + quad * 4;
  const int colbase = xt * 128 + wn + l16;
#pragma unroll
  for (int j = 0; j < 4; j++) {
    const int n = colbase + j * 16;
    const float bv = bias[e * HIDDEN + n];
#pragma unroll
    for (int i = 0; i < 4; i++) {
      const int m0 = rowbase + i * 16;
#pragma unroll
      for (int r = 0; r < 4; r++) {
        float v = acc[i][j][r] + bv;
        v = v > 0.0f ? v : 0.0f;
        const int m = m0 + r;
        if (SECOND) {
          const int b = perm[m];
          if (b >= 0) Yout[(size_t)b * HIDDEN + n] = v;
        } else {
          Hout[(size_t)m * HIDDEN + n] = (short)f2bf(v);
        }
      }
    }
  }
}

extern "C" void kernel_launch(void* const* d_in, const int* in_sizes, int n_in,
                              void* d_out, int out_size, void* d_ws, size_t ws_size,
                              hipStream_t stream) {
  const float* x  = (const float*)d_in[0];
  const float* W1 = (const float*)d_in[1];
  const float* b1 = (const float*)d_in[2];
  const float* W2 = (const float*)d_in[3];
  const float* b2 = (const float*)d_in[4];
  const int* ops  = (const int*)d_in[5];
  float* out = (float*)d_out;

  char* ws = (char*)d_ws;
  short* xb  = (short*)(ws);
  short* h   = (short*)(ws + XB_SZ);
  short* w1t = (short*)(ws + XB_SZ + H_SZ);
  short* w2t = (short*)(ws + XB_SZ + H_SZ + WT_SZ);
  int* perm  = (int*)(ws + XB_SZ + H_SZ + 2 * WT_SZ);
  int* meta  = (int*)(ws + XB_SZ + H_SZ + 2 * WT_SZ + PERM_SZ);
  int* cnt = meta;       // [3]
  int* c2  = meta + 4;   // [3]
  int* seg = meta + 8;   // [4]
  int* te  = meta + 16;  // [NTILES]

  hipMemsetAsync(meta, 0, 32, stream);                       // cnt + c2
  k_count<<<(M_CAP + 255) / 256, 256, 0, stream>>>(ops, cnt, perm);
  k_scan<<<1, 64, 0, stream>>>(cnt, seg, te);
  k_perm<<<BATCH / 256, 256, 0, stream>>>(ops, seg, c2, perm);
  k_prep<<<M_CAP + 6 * 32 * 32, 256, 0, stream>>>(x, perm, xb, W1, W2, w1t, w2t);
  gemm_fused<0><<<NXT * NTILES, 256, 0, stream>>>(xb, w1t, b1, te, perm, h, nullptr);
  gemm_fused<1><<<NXT * NTILES, 256, 0, stream>>>(h, w2t, b2, te, perm, nullptr, out);
}